// Round 1
// baseline (1847.391 us; speedup 1.0000x reference)
//
#include <hip/hip_runtime.h>
#include <math.h>

#define N_NODES 50000
#define N_EDGES 800000
#define N_GRAPH 1024
#define CDIM 128
#define FINDIM 16
#define NL 3

using short8  = __attribute__((ext_vector_type(8))) short;
using floatx4 = __attribute__((ext_vector_type(4))) float;

__device__ __forceinline__ float sspf(float x) {
    // softplus(x) - ln2, numerically stable
    float a  = fabsf(x);
    float sp = fmaxf(x, 0.0f) + log1pf(__expf(-a));
    return sp - 0.6931471805599453f;
}

__device__ __forceinline__ unsigned short f2bf(float f) {
    unsigned int u = __float_as_uint(f);
    u = u + 0x7FFFu + ((u >> 16) & 1u);   // round-to-nearest-even
    return (unsigned short)(u >> 16);
}

// ---------------------------------------------------------------- embedding
// Linear(16,128) -> Linear(128,128) collapses: Wf = Wl1@Wl2, bf = bl1@Wl2+bl2
__global__ void k_fuse(const float* __restrict__ Wl1, const float* __restrict__ bl1,
                       const float* __restrict__ Wl2, const float* __restrict__ bl2,
                       float* __restrict__ Wf, float* __restrict__ bfv) {
    for (int o = threadIdx.x; o < FINDIM * CDIM + CDIM; o += 256) {
        if (o < FINDIM * CDIM) {
            int f = o >> 7, c = o & 127;
            float s = 0.f;
            for (int k = 0; k < CDIM; ++k) s += Wl1[f * CDIM + k] * Wl2[k * CDIM + c];
            Wf[o] = s;
        } else {
            int c = o - FINDIM * CDIM;
            float s = bl2[c];
            for (int k = 0; k < CDIM; ++k) s += bl1[k] * Wl2[k * CDIM + c];
            bfv[c] = s;
        }
    }
}

__global__ void k_embed(const float* __restrict__ x, const float* __restrict__ Wf,
                        const float* __restrict__ bfv, float* __restrict__ h) {
    __shared__ float wfs[FINDIM * CDIM];
    __shared__ float bfs[CDIM];
    for (int o = threadIdx.x; o < FINDIM * CDIM; o += 256) wfs[o] = Wf[o];
    if (threadIdx.x < CDIM) bfs[threadIdx.x] = bfv[threadIdx.x];
    __syncthreads();
    int c = threadIdx.x & 127;
    int half = threadIdx.x >> 7;
    for (int base = blockIdx.x * 2; base < N_NODES; base += gridDim.x * 2) {
        int n = base + half;
        if (n < N_NODES) {
            float s = bfs[c];
            const float* xp = x + (size_t)n * FINDIM;
#pragma unroll
            for (int f = 0; f < FINDIM; ++f) s += xp[f] * wfs[f * CDIM + c];
            h[(size_t)n * CDIM + c] = s;
        }
    }
}

// ---------------------------------------------------------------- batchnorm
__global__ void k_bnstats(const float* __restrict__ h, float* __restrict__ bnsum) {
    __shared__ float sd[512];
    int c = threadIdx.x & 127, half = threadIdx.x >> 7;
    float s = 0.f, s2 = 0.f;
    for (int r = blockIdx.x * 2 + half; r < N_NODES; r += gridDim.x * 2) {
        float v = h[(size_t)r * CDIM + c];
        s += v; s2 += v * v;
    }
    sd[threadIdx.x] = s; sd[256 + threadIdx.x] = s2;
    __syncthreads();
    if (threadIdx.x < 128) {
        atomicAdd(&bnsum[threadIdx.x], sd[threadIdx.x] + sd[threadIdx.x + 128]);
        atomicAdd(&bnsum[128 + threadIdx.x], sd[256 + threadIdx.x] + sd[256 + threadIdx.x + 128]);
    }
}

__global__ void k_bnapply(float* __restrict__ h, const float* __restrict__ bnsum,
                          const float* __restrict__ g, const float* __restrict__ b) {
    const float invN = 1.0f / (float)N_NODES;
    for (size_t i = (size_t)blockIdx.x * 256 + threadIdx.x; i < (size_t)N_NODES * CDIM;
         i += (size_t)gridDim.x * 256) {
        int c = (int)(i & 127);
        float mu  = bnsum[c] * invN;
        float var = bnsum[128 + c] * invN - mu * mu;
        float sc  = g[c] * rsqrtf(var + 1e-5f);
        h[i] = (h[i] - mu) * sc + b[c];
    }
}

// ---------------------------------------------------------------- node GEMM (bf16 MFMA)
// MODE 0: Out = A@B + bias            (hin)
// MODE 1: Out += ssp(A@B + bias)      (residual update of h from agg)
template <int MODE>
__global__ __launch_bounds__(256, 2) void k_ngemm(const float* __restrict__ A,
                                                  const float* __restrict__ B,
                                                  const float* __restrict__ bias,
                                                  float* __restrict__ Out) {
    __shared__ unsigned short WT[128 * 136];   // B^T bf16, padded (2-way LDS conflict = free)
    __shared__ float bs[CDIM];
    for (int o = threadIdx.x; o < CDIM * CDIM; o += 256) {
        int k = o >> 7, c = o & 127;
        WT[c * 136 + k] = f2bf(B[o]);
    }
    if (threadIdx.x < CDIM) bs[threadIdx.x] = bias[threadIdx.x];
    __syncthreads();

    int lane = threadIdx.x & 63, wave = threadIdx.x >> 6;
    int m = lane & 15, q = lane >> 4;
    int rb = blockIdx.x * 64 + wave * 16;
    int row = rb + m;
    if (row > N_NODES - 1) row = N_NODES - 1;

    floatx4 acc[8];
#pragma unroll
    for (int nt = 0; nt < 8; ++nt) acc[nt] = (floatx4){0.f, 0.f, 0.f, 0.f};

#pragma unroll
    for (int kb = 0; kb < 4; ++kb) {
        int k0 = kb * 32 + q * 8;
        const float* ap = A + (size_t)row * CDIM + k0;
        float4 lo = *(const float4*)ap;
        float4 hi = *(const float4*)(ap + 4);
        short8 af;
        af[0] = (short)f2bf(lo.x); af[1] = (short)f2bf(lo.y);
        af[2] = (short)f2bf(lo.z); af[3] = (short)f2bf(lo.w);
        af[4] = (short)f2bf(hi.x); af[5] = (short)f2bf(hi.y);
        af[6] = (short)f2bf(hi.z); af[7] = (short)f2bf(hi.w);
#pragma unroll
        for (int nt = 0; nt < 8; ++nt) {
            short8 bf = *(const short8*)&WT[(nt * 16 + m) * 136 + k0];
            acc[nt] = __builtin_amdgcn_mfma_f32_16x16x32_bf16(af, bf, acc[nt], 0, 0, 0);
        }
    }
    // C layout: col = lane&15 (=m), row = q*4 + r  [m89-verified]
#pragma unroll
    for (int nt = 0; nt < 8; ++nt) {
        int c = nt * 16 + m;
#pragma unroll
        for (int r = 0; r < 4; ++r) {
            int orow = rb + q * 4 + r;
            if (orow < N_NODES) {
                float v = acc[nt][r] + bs[c];
                if (MODE == 0) Out[(size_t)orow * CDIM + c] = v;
                else           Out[(size_t)orow * CDIM + c] += sspf(v);
            }
        }
    }
}

// ---------------------------------------------------------------- fused edge kernel
// per edge: t = ssp(ea@We1+be1); filt = t@We2+be2 (MFMA, B in registers);
// msg = hin[src]*filt*env; atomicAdd agg[dst]
__global__ __launch_bounds__(256, 2) void k_edge(
    const float* __restrict__ We1, const float* __restrict__ be1,
    const float* __restrict__ We2, const float* __restrict__ be2,
    const float* __restrict__ edge_attr, const float* __restrict__ edge_weight,
    const int* __restrict__ esrc, const int* __restrict__ edst,
    const float* __restrict__ hin, float* __restrict__ agg) {
    __shared__ unsigned short WT[128 * 136];   // We2^T bf16 (staging for breg)
    __shared__ unsigned short TL[64 * 136];    // t bf16, 64 edges x 128 k
    __shared__ float we1s[3 * CDIM];
    __shared__ float be1s[CDIM];
    __shared__ float be2s[CDIM];
    __shared__ float eas[64 * 3];
    __shared__ float envs[64];
    __shared__ int   srcs[64];
    __shared__ int   dsts[64];

    for (int o = threadIdx.x; o < CDIM * CDIM; o += 256) {
        int k = o >> 7, c = o & 127;
        WT[c * 136 + k] = f2bf(We2[o]);
    }
    for (int o = threadIdx.x; o < 3 * CDIM; o += 256) we1s[o] = We1[o];
    if (threadIdx.x < CDIM) { be1s[threadIdx.x] = be1[threadIdx.x]; be2s[threadIdx.x] = be2[threadIdx.x]; }
    __syncthreads();

    int lane = threadIdx.x & 63, wave = threadIdx.x >> 6;
    int m = lane & 15, q = lane >> 4;

    // cache all B fragments in registers (B is loop-invariant): 32 x short8 = 128 VGPRs
    short8 breg[4][8];
#pragma unroll
    for (int kb = 0; kb < 4; ++kb)
#pragma unroll
        for (int nt = 0; nt < 8; ++nt)
            breg[kb][nt] = *(const short8*)&WT[(nt * 16 + m) * 136 + kb * 32 + q * 8];

    const int ntiles = N_EDGES / 64;
    for (int tile = blockIdx.x; tile < ntiles; tile += gridDim.x) {
        int e0 = tile * 64;
        __syncthreads();   // previous iteration's readers done before re-staging
        if (threadIdx.x < 64) {
            int e = e0 + threadIdx.x;
            srcs[threadIdx.x] = esrc[e];
            dsts[threadIdx.x] = edst[e];
            float w = edge_weight[e];
            envs[threadIdx.x] = 0.5f * (__cosf(w * 0.31415926535897932f) + 1.0f);
        }
        if (threadIdx.x < 192) eas[threadIdx.x] = edge_attr[(size_t)e0 * 3 + threadIdx.x];
        __syncthreads();

        // t-compute: wave w handles k in [w*32, w*32+32), el = lane
        {
            int el = lane;
            float ea0 = eas[el * 3], ea1 = eas[el * 3 + 1], ea2 = eas[el * 3 + 2];
            int kqb = wave * 32;
#pragma unroll
            for (int j = 0; j < 32; j += 2) {
                int k = kqb + j;
                float p0 = we1s[k] * ea0 + we1s[CDIM + k] * ea1 + we1s[2 * CDIM + k] * ea2 + be1s[k];
                float p1 = we1s[k + 1] * ea0 + we1s[CDIM + k + 1] * ea1 + we1s[2 * CDIM + k + 1] * ea2 + be1s[k + 1];
                unsigned int pk = (unsigned int)f2bf(sspf(p0)) | ((unsigned int)f2bf(sspf(p1)) << 16);
                *(unsigned int*)&TL[el * 136 + k] = pk;
            }
        }
        __syncthreads();

        floatx4 acc[8];
#pragma unroll
        for (int nt = 0; nt < 8; ++nt) acc[nt] = (floatx4){0.f, 0.f, 0.f, 0.f};
#pragma unroll
        for (int kb = 0; kb < 4; ++kb) {
            short8 af = *(const short8*)&TL[(wave * 16 + m) * 136 + kb * 32 + q * 8];
#pragma unroll
            for (int nt = 0; nt < 8; ++nt)
                acc[nt] = __builtin_amdgcn_mfma_f32_16x16x32_bf16(af, breg[kb][nt], acc[nt], 0, 0, 0);
        }

        // epilogue: filt -> msg -> scatter-add
#pragma unroll
        for (int r = 0; r < 4; ++r) {
            int el = wave * 16 + q * 4 + r;
            int s = srcs[el], d = dsts[el];
            float ev = envs[el];
            const float* hp = hin + (size_t)s * CDIM;
            float* ap = agg + (size_t)d * CDIM;
#pragma unroll
            for (int nt = 0; nt < 8; ++nt) {
                int c = nt * 16 + m;
                float msg = (acc[nt][r] + be2s[c]) * ev * hp[c];
                atomicAdd(&ap[c], msg);
            }
        }
    }
}

// ---------------------------------------------------------------- readout
__global__ void k_pool(const float* __restrict__ h, const int* __restrict__ batch,
                       float* __restrict__ hg) {
    for (size_t i = (size_t)blockIdx.x * 256 + threadIdx.x; i < (size_t)N_NODES * CDIM;
         i += (size_t)gridDim.x * 256) {
        int n = (int)(i >> 7), c = (int)(i & 127);
        atomicAdd(&hg[(size_t)batch[n] * CDIM + c], h[i]);
    }
}

__global__ void k_readout(const float* __restrict__ hg, const float* __restrict__ Wr1,
                          const float* __restrict__ br1, const float* __restrict__ Wr2,
                          const float* __restrict__ br2, float* __restrict__ out) {
    __shared__ float hgs[CDIM];
    int g = blockIdx.x;
    for (int o = threadIdx.x; o < CDIM; o += 64) hgs[o] = hg[(size_t)g * CDIM + o];
    __syncthreads();
    int c = threadIdx.x;
    float val = 0.f;
    if (c < 32) {
        float s = br1[c];
        for (int k = 0; k < CDIM; ++k) s += hgs[k] * Wr1[k * 32 + c];
        val = sspf(s) * Wr2[c];
    }
#pragma unroll
    for (int off = 16; off >= 1; off >>= 1) val += __shfl_down(val, off, 32);
    if (c == 0) out[g] = sspf(val + br2[0]);
}

// ---------------------------------------------------------------- launch
extern "C" void kernel_launch(void* const* d_in, const int* in_sizes, int n_in,
                              void* d_out, int out_size, void* d_ws, size_t ws_size,
                              hipStream_t stream) {
    const float* x     = (const float*)d_in[0];
    const int*   eidx  = (const int*)  d_in[1];
    const float* ew    = (const float*)d_in[2];
    const float* ea    = (const float*)d_in[3];
    const int*   batch = (const int*)  d_in[4];
    const float* Wl1   = (const float*)d_in[5];
    const float* bl1   = (const float*)d_in[6];
    const float* Wl2   = (const float*)d_in[7];
    const float* bl2   = (const float*)d_in[8];
    const float* bng   = (const float*)d_in[9];
    const float* bnb   = (const float*)d_in[10];
    const float* Wi_in = (const float*)d_in[11];
    const float* bi_in = (const float*)d_in[12];
    const float* We1   = (const float*)d_in[13];
    const float* be1   = (const float*)d_in[14];
    const float* We2   = (const float*)d_in[15];
    const float* be2   = (const float*)d_in[16];
    const float* Wi_o  = (const float*)d_in[17];
    const float* bi_o  = (const float*)d_in[18];
    const float* Wr1   = (const float*)d_in[19];
    const float* br1   = (const float*)d_in[20];
    const float* Wr2   = (const float*)d_in[21];
    const float* br2   = (const float*)d_in[22];
    float* out = (float*)d_out;

    float* ws    = (float*)d_ws;
    float* h     = ws;                                   // N*128
    float* hin   = h   + (size_t)N_NODES * CDIM;         // N*128
    float* agg   = hin + (size_t)N_NODES * CDIM;         // N*128
    float* hg    = agg + (size_t)N_NODES * CDIM;         // G*128
    float* Wf    = hg  + (size_t)N_GRAPH * CDIM;         // 16*128
    float* bfv   = Wf  + FINDIM * CDIM;                  // 128
    float* bnsum = bfv + CDIM;                           // 256

    const int* esrc = eidx;
    const int* edst = eidx + N_EDGES;

    k_fuse<<<1, 256, 0, stream>>>(Wl1, bl1, Wl2, bl2, Wf, bfv);
    k_embed<<<512, 256, 0, stream>>>(x, Wf, bfv, h);
    hipMemsetAsync(bnsum, 0, 256 * sizeof(float), stream);
    k_bnstats<<<512, 256, 0, stream>>>(h, bnsum);
    k_bnapply<<<1024, 256, 0, stream>>>(h, bnsum, bng, bnb);

    const int ngrid = (N_NODES + 63) / 64;
    for (int l = 0; l < NL; ++l) {
        hipMemsetAsync(agg, 0, (size_t)N_NODES * CDIM * sizeof(float), stream);
        k_ngemm<0><<<ngrid, 256, 0, stream>>>(h, Wi_in + (size_t)l * CDIM * CDIM,
                                              bi_in + l * CDIM, hin);
        k_edge<<<512, 256, 0, stream>>>(We1 + l * 3 * CDIM, be1 + l * CDIM,
                                        We2 + (size_t)l * CDIM * CDIM, be2 + l * CDIM,
                                        ea, ew, esrc, edst, hin, agg);
        k_ngemm<1><<<ngrid, 256, 0, stream>>>(agg, Wi_o + (size_t)l * CDIM * CDIM,
                                              bi_o + l * CDIM, h);
    }
    hipMemsetAsync(hg, 0, (size_t)N_GRAPH * CDIM * sizeof(float), stream);
    k_pool<<<2048, 256, 0, stream>>>(h, batch, hg);
    k_readout<<<N_GRAPH, 64, 0, stream>>>(hg, Wr1, br1, Wr2, br2, out);
}

// Round 2
// 1678.151 us; speedup vs baseline: 1.1008x; 1.1008x over previous
//
#include <hip/hip_runtime.h>
#include <math.h>

#define N_NODES 50000
#define N_EDGES 800000
#define N_GRAPH 1024
#define CDIM 128
#define FINDIM 16
#define NL 3

using short8  = __attribute__((ext_vector_type(8))) short;
using floatx4 = __attribute__((ext_vector_type(4))) float;

__device__ __forceinline__ float sspf(float x) {
    // softplus(x) - ln2 via HW v_exp_f32/v_log_f32 (~6 VALU ops, no libm log1pf)
    // abs err <= ~6e-8 vs exact (1+y rounding), far below bf16 noise floor
    return fmaxf(x, 0.0f) + __logf(1.0f + __expf(-fabsf(x))) - 0.6931471805599453f;
}

__device__ __forceinline__ unsigned short f2bf(float f) {
    unsigned int u = __float_as_uint(f);
    u = u + 0x7FFFu + ((u >> 16) & 1u);   // round-to-nearest-even
    return (unsigned short)(u >> 16);
}

// ---------------------------------------------------------------- embedding
__global__ void k_fuse(const float* __restrict__ Wl1, const float* __restrict__ bl1,
                       const float* __restrict__ Wl2, const float* __restrict__ bl2,
                       float* __restrict__ Wf, float* __restrict__ bfv) {
    for (int o = threadIdx.x; o < FINDIM * CDIM + CDIM; o += 256) {
        if (o < FINDIM * CDIM) {
            int f = o >> 7, c = o & 127;
            float s = 0.f;
            for (int k = 0; k < CDIM; ++k) s += Wl1[f * CDIM + k] * Wl2[k * CDIM + c];
            Wf[o] = s;
        } else {
            int c = o - FINDIM * CDIM;
            float s = bl2[c];
            for (int k = 0; k < CDIM; ++k) s += bl1[k] * Wl2[k * CDIM + c];
            bfv[c] = s;
        }
    }
}

__global__ void k_embed(const float* __restrict__ x, const float* __restrict__ Wf,
                        const float* __restrict__ bfv, float* __restrict__ h) {
    __shared__ float wfs[FINDIM * CDIM];
    __shared__ float bfs[CDIM];
    for (int o = threadIdx.x; o < FINDIM * CDIM; o += 256) wfs[o] = Wf[o];
    if (threadIdx.x < CDIM) bfs[threadIdx.x] = bfv[threadIdx.x];
    __syncthreads();
    int c = threadIdx.x & 127;
    int half = threadIdx.x >> 7;
    for (int base = blockIdx.x * 2; base < N_NODES; base += gridDim.x * 2) {
        int n = base + half;
        if (n < N_NODES) {
            float s = bfs[c];
            const float* xp = x + (size_t)n * FINDIM;
#pragma unroll
            for (int f = 0; f < FINDIM; ++f) s += xp[f] * wfs[f * CDIM + c];
            h[(size_t)n * CDIM + c] = s;
        }
    }
}

// ---------------------------------------------------------------- batchnorm
__global__ void k_bnstats(const float* __restrict__ h, float* __restrict__ bnsum) {
    __shared__ float sd[512];
    int c = threadIdx.x & 127, half = threadIdx.x >> 7;
    float s = 0.f, s2 = 0.f;
    for (int r = blockIdx.x * 2 + half; r < N_NODES; r += gridDim.x * 2) {
        float v = h[(size_t)r * CDIM + c];
        s += v; s2 += v * v;
    }
    sd[threadIdx.x] = s; sd[256 + threadIdx.x] = s2;
    __syncthreads();
    if (threadIdx.x < 128) {
        atomicAdd(&bnsum[threadIdx.x], sd[threadIdx.x] + sd[threadIdx.x + 128]);
        atomicAdd(&bnsum[128 + threadIdx.x], sd[256 + threadIdx.x] + sd[256 + threadIdx.x + 128]);
    }
}

__global__ void k_bnapply(float* __restrict__ h, const float* __restrict__ bnsum,
                          const float* __restrict__ g, const float* __restrict__ b) {
    const float invN = 1.0f / (float)N_NODES;
    for (size_t i = (size_t)blockIdx.x * 256 + threadIdx.x; i < (size_t)N_NODES * CDIM;
         i += (size_t)gridDim.x * 256) {
        int c = (int)(i & 127);
        float mu  = bnsum[c] * invN;
        float var = bnsum[128 + c] * invN - mu * mu;
        float sc  = g[c] * rsqrtf(var + 1e-5f);
        h[i] = (h[i] - mu) * sc + b[c];
    }
}

// ---------------------------------------------------------------- dst count-sort (once/call)
__global__ void k_hist(const int* __restrict__ edst, int* __restrict__ deg) {
    int e = blockIdx.x * 256 + threadIdx.x;
    if (e < N_EDGES) atomicAdd(&deg[edst[e]], 1);
}

#define SCAN_T 1024
#define CHUNK 49   // 1024*49 = 50176 >= 50000
__global__ void k_scan(const int* __restrict__ deg, int* __restrict__ row_ptr) {
    __shared__ int part[SCAN_T];
    int t = threadIdx.x;
    int begin = t * CHUNK;
    int end   = begin + CHUNK; if (end > N_NODES) end = N_NODES;
    int s = 0;
    for (int i = begin; i < end && i < N_NODES; ++i) s += deg[i];
    part[t] = s;
    __syncthreads();
    for (int off = 1; off < SCAN_T; off <<= 1) {
        int v = (t >= off) ? part[t - off] : 0;
        __syncthreads();
        part[t] += v;
        __syncthreads();
    }
    int run = (t == 0) ? 0 : part[t - 1];
    for (int i = begin; i < end && i < N_NODES; ++i) { row_ptr[i] = run; run += deg[i]; }
    if (t == SCAN_T - 1) row_ptr[N_NODES] = run;
}

__global__ void k_scatter(const int* __restrict__ edst, const int* __restrict__ row_ptr,
                          int* __restrict__ cnt, int* __restrict__ perm) {
    int e = blockIdx.x * 256 + threadIdx.x;
    if (e < N_EDGES) {
        int d = edst[e];
        int pos = row_ptr[d] + atomicAdd(&cnt[d], 1);
        perm[pos] = e;
    }
}

// ---------------------------------------------------------------- node GEMM (bf16 MFMA)
template <int MODE>
__global__ __launch_bounds__(256, 2) void k_ngemm(const float* __restrict__ A,
                                                  const float* __restrict__ B,
                                                  const float* __restrict__ bias,
                                                  float* __restrict__ Out) {
    __shared__ unsigned short WT[128 * 136];
    __shared__ float bs[CDIM];
    for (int o = threadIdx.x; o < CDIM * CDIM; o += 256) {
        int k = o >> 7, c = o & 127;
        WT[c * 136 + k] = f2bf(B[o]);
    }
    if (threadIdx.x < CDIM) bs[threadIdx.x] = bias[threadIdx.x];
    __syncthreads();

    int lane = threadIdx.x & 63, wave = threadIdx.x >> 6;
    int m = lane & 15, q = lane >> 4;
    int rb = blockIdx.x * 64 + wave * 16;
    int row = rb + m;
    if (row > N_NODES - 1) row = N_NODES - 1;

    floatx4 acc[8];
#pragma unroll
    for (int nt = 0; nt < 8; ++nt) acc[nt] = (floatx4){0.f, 0.f, 0.f, 0.f};

#pragma unroll
    for (int kb = 0; kb < 4; ++kb) {
        int k0 = kb * 32 + q * 8;
        const float* ap = A + (size_t)row * CDIM + k0;
        float4 lo = *(const float4*)ap;
        float4 hi = *(const float4*)(ap + 4);
        short8 af;
        af[0] = (short)f2bf(lo.x); af[1] = (short)f2bf(lo.y);
        af[2] = (short)f2bf(lo.z); af[3] = (short)f2bf(lo.w);
        af[4] = (short)f2bf(hi.x); af[5] = (short)f2bf(hi.y);
        af[6] = (short)f2bf(hi.z); af[7] = (short)f2bf(hi.w);
#pragma unroll
        for (int nt = 0; nt < 8; ++nt) {
            short8 bf = *(const short8*)&WT[(nt * 16 + m) * 136 + k0];
            acc[nt] = __builtin_amdgcn_mfma_f32_16x16x32_bf16(af, bf, acc[nt], 0, 0, 0);
        }
    }
#pragma unroll
    for (int nt = 0; nt < 8; ++nt) {
        int c = nt * 16 + m;
#pragma unroll
        for (int r = 0; r < 4; ++r) {
            int orow = rb + q * 4 + r;
            if (orow < N_NODES) {
                float v = acc[nt][r] + bs[c];
                if (MODE == 0) Out[(size_t)orow * CDIM + c] = v;
                else           Out[(size_t)orow * CDIM + c] += sspf(v);
            }
        }
    }
}

// ---------------------------------------------------------------- fused edge kernel (dst-sorted)
__global__ __launch_bounds__(256, 2) void k_edge(
    const float* __restrict__ We1, const float* __restrict__ be1,
    const float* __restrict__ We2, const float* __restrict__ be2,
    const float* __restrict__ edge_attr, const float* __restrict__ edge_weight,
    const int* __restrict__ esrc, const int* __restrict__ edst,
    const int* __restrict__ perm,
    const float* __restrict__ hin, float* __restrict__ agg) {
    __shared__ unsigned short WT[128 * 136];
    __shared__ unsigned short TL[64 * 136];
    __shared__ float we1s[3 * CDIM];
    __shared__ float be1s[CDIM];
    __shared__ float be2s[CDIM];
    __shared__ float eas[64 * 3];
    __shared__ float envs[64];
    __shared__ int   srcs[64];
    __shared__ int   dsts[64];

    for (int o = threadIdx.x; o < CDIM * CDIM; o += 256) {
        int k = o >> 7, c = o & 127;
        WT[c * 136 + k] = f2bf(We2[o]);
    }
    for (int o = threadIdx.x; o < 3 * CDIM; o += 256) we1s[o] = We1[o];
    if (threadIdx.x < CDIM) { be1s[threadIdx.x] = be1[threadIdx.x]; be2s[threadIdx.x] = be2[threadIdx.x]; }
    __syncthreads();

    int lane = threadIdx.x & 63, wave = threadIdx.x >> 6;
    int m = lane & 15, q = lane >> 4;

    short8 breg[4][8];
#pragma unroll
    for (int kb = 0; kb < 4; ++kb)
#pragma unroll
        for (int nt = 0; nt < 8; ++nt)
            breg[kb][nt] = *(const short8*)&WT[(nt * 16 + m) * 136 + kb * 32 + q * 8];

    // contiguous tile range per block -> each block's dst window is small & L2-local
    const int ntiles = N_EDGES / 64;
    int tpb = (ntiles + gridDim.x - 1) / gridDim.x;
    int t0 = blockIdx.x * tpb;
    int t1 = t0 + tpb; if (t1 > ntiles) t1 = ntiles;

    for (int tile = t0; tile < t1; ++tile) {
        int s0 = tile * 64;
        __syncthreads();
        if (threadIdx.x < 64) {
            int e = perm[s0 + threadIdx.x];
            srcs[threadIdx.x] = esrc[e];
            dsts[threadIdx.x] = edst[e];
            float w = edge_weight[e];
            envs[threadIdx.x] = 0.5f * (__cosf(w * 0.31415926535897932f) + 1.0f);
            eas[threadIdx.x * 3 + 0] = edge_attr[(size_t)e * 3 + 0];
            eas[threadIdx.x * 3 + 1] = edge_attr[(size_t)e * 3 + 1];
            eas[threadIdx.x * 3 + 2] = edge_attr[(size_t)e * 3 + 2];
        }
        __syncthreads();

        // t = ssp(ea @ We1 + be1), each lane = one edge, wave covers 32 k
        {
            int el = lane;
            float ea0 = eas[el * 3], ea1 = eas[el * 3 + 1], ea2 = eas[el * 3 + 2];
            int kqb = wave * 32;
#pragma unroll
            for (int j = 0; j < 32; j += 2) {
                int k = kqb + j;
                float p0 = we1s[k] * ea0 + we1s[CDIM + k] * ea1 + we1s[2 * CDIM + k] * ea2 + be1s[k];
                float p1 = we1s[k + 1] * ea0 + we1s[CDIM + k + 1] * ea1 + we1s[2 * CDIM + k + 1] * ea2 + be1s[k + 1];
                unsigned int pk = (unsigned int)f2bf(sspf(p0)) | ((unsigned int)f2bf(sspf(p1)) << 16);
                *(unsigned int*)&TL[el * 136 + k] = pk;
            }
        }
        __syncthreads();

        floatx4 acc[8];
#pragma unroll
        for (int nt = 0; nt < 8; ++nt) acc[nt] = (floatx4){0.f, 0.f, 0.f, 0.f};
#pragma unroll
        for (int kb = 0; kb < 4; ++kb) {
            short8 af = *(const short8*)&TL[(wave * 16 + m) * 136 + kb * 32 + q * 8];
#pragma unroll
            for (int nt = 0; nt < 8; ++nt)
                acc[nt] = __builtin_amdgcn_mfma_f32_16x16x32_bf16(af, breg[kb][nt], acc[nt], 0, 0, 0);
        }

        // epilogue: dst-sorted run-merge over the thread's 4 consecutive edges
        int el0 = wave * 16 + q * 4;
#pragma unroll
        for (int nt = 0; nt < 8; ++nt) {
            int c = nt * 16 + m;
            int cur = dsts[el0];
            float accv = 0.f;
#pragma unroll
            for (int r = 0; r < 4; ++r) {
                int el = el0 + r;
                int d = dsts[el];
                float msg = (acc[nt][r] + be2s[c]) * envs[el] * hin[(size_t)srcs[el] * CDIM + c];
                if (d != cur) {
                    atomicAdd(&agg[(size_t)cur * CDIM + c], accv);
                    cur = d; accv = msg;
                } else {
                    accv += msg;
                }
            }
            atomicAdd(&agg[(size_t)cur * CDIM + c], accv);
        }
    }
}

// ---------------------------------------------------------------- readout
__global__ void k_pool(const float* __restrict__ h, const int* __restrict__ batch,
                       float* __restrict__ hg) {
    for (size_t i = (size_t)blockIdx.x * 256 + threadIdx.x; i < (size_t)N_NODES * CDIM;
         i += (size_t)gridDim.x * 256) {
        int n = (int)(i >> 7), c = (int)(i & 127);
        atomicAdd(&hg[(size_t)batch[n] * CDIM + c], h[i]);
    }
}

__global__ void k_readout(const float* __restrict__ hg, const float* __restrict__ Wr1,
                          const float* __restrict__ br1, const float* __restrict__ Wr2,
                          const float* __restrict__ br2, float* __restrict__ out) {
    __shared__ float hgs[CDIM];
    int g = blockIdx.x;
    for (int o = threadIdx.x; o < CDIM; o += 64) hgs[o] = hg[(size_t)g * CDIM + o];
    __syncthreads();
    int c = threadIdx.x;
    float val = 0.f;
    if (c < 32) {
        float s = br1[c];
        for (int k = 0; k < CDIM; ++k) s += hgs[k] * Wr1[k * 32 + c];
        val = sspf(s) * Wr2[c];
    }
#pragma unroll
    for (int off = 16; off >= 1; off >>= 1) val += __shfl_down(val, off, 32);
    if (c == 0) out[g] = sspf(val + br2[0]);
}

// ---------------------------------------------------------------- launch
extern "C" void kernel_launch(void* const* d_in, const int* in_sizes, int n_in,
                              void* d_out, int out_size, void* d_ws, size_t ws_size,
                              hipStream_t stream) {
    const float* x     = (const float*)d_in[0];
    const int*   eidx  = (const int*)  d_in[1];
    const float* ew    = (const float*)d_in[2];
    const float* ea    = (const float*)d_in[3];
    const int*   batch = (const int*)  d_in[4];
    const float* Wl1   = (const float*)d_in[5];
    const float* bl1   = (const float*)d_in[6];
    const float* Wl2   = (const float*)d_in[7];
    const float* bl2   = (const float*)d_in[8];
    const float* bng   = (const float*)d_in[9];
    const float* bnb   = (const float*)d_in[10];
    const float* Wi_in = (const float*)d_in[11];
    const float* bi_in = (const float*)d_in[12];
    const float* We1   = (const float*)d_in[13];
    const float* be1   = (const float*)d_in[14];
    const float* We2   = (const float*)d_in[15];
    const float* be2   = (const float*)d_in[16];
    const float* Wi_o  = (const float*)d_in[17];
    const float* bi_o  = (const float*)d_in[18];
    const float* Wr1   = (const float*)d_in[19];
    const float* br1   = (const float*)d_in[20];
    const float* Wr2   = (const float*)d_in[21];
    const float* br2   = (const float*)d_in[22];
    float* out = (float*)d_out;

    float* ws    = (float*)d_ws;
    float* h     = ws;                                   // N*128
    float* hin   = h   + (size_t)N_NODES * CDIM;         // N*128
    float* agg   = hin + (size_t)N_NODES * CDIM;         // N*128
    float* hg    = agg + (size_t)N_NODES * CDIM;         // G*128
    float* Wf    = hg  + (size_t)N_GRAPH * CDIM;         // 16*128
    float* bfv   = Wf  + FINDIM * CDIM;                  // 128
    float* bnsum = bfv + CDIM;                           // 256
    int*   deg     = (int*)(bnsum + 256);                // N
    int*   row_ptr = deg + N_NODES;                      // N+1
    int*   cnt     = row_ptr + N_NODES + 1;              // N
    int*   perm    = cnt + N_NODES;                      // E

    const int* esrc = eidx;
    const int* edst = eidx + N_EDGES;

    // ---- edge sort by dst (reused across the 3 layers)
    hipMemsetAsync(deg, 0, (size_t)N_NODES * sizeof(int), stream);
    hipMemsetAsync(cnt, 0, (size_t)N_NODES * sizeof(int), stream);
    k_hist<<<(N_EDGES + 255) / 256, 256, 0, stream>>>(edst, deg);
    k_scan<<<1, SCAN_T, 0, stream>>>(deg, row_ptr);
    k_scatter<<<(N_EDGES + 255) / 256, 256, 0, stream>>>(edst, row_ptr, cnt, perm);

    // ---- embedding + BN
    k_fuse<<<1, 256, 0, stream>>>(Wl1, bl1, Wl2, bl2, Wf, bfv);
    k_embed<<<512, 256, 0, stream>>>(x, Wf, bfv, h);
    hipMemsetAsync(bnsum, 0, 256 * sizeof(float), stream);
    k_bnstats<<<512, 256, 0, stream>>>(h, bnsum);
    k_bnapply<<<1024, 256, 0, stream>>>(h, bnsum, bng, bnb);

    // ---- interaction layers
    const int ngrid = (N_NODES + 63) / 64;
    for (int l = 0; l < NL; ++l) {
        hipMemsetAsync(agg, 0, (size_t)N_NODES * CDIM * sizeof(float), stream);
        k_ngemm<0><<<ngrid, 256, 0, stream>>>(h, Wi_in + (size_t)l * CDIM * CDIM,
                                              bi_in + l * CDIM, hin);
        k_edge<<<512, 256, 0, stream>>>(We1 + l * 3 * CDIM, be1 + l * CDIM,
                                        We2 + (size_t)l * CDIM * CDIM, be2 + l * CDIM,
                                        ea, ew, esrc, edst, perm, hin, agg);
        k_ngemm<1><<<ngrid, 256, 0, stream>>>(agg, Wi_o + (size_t)l * CDIM * CDIM,
                                              bi_o + l * CDIM, h);
    }

    // ---- readout
    hipMemsetAsync(hg, 0, (size_t)N_GRAPH * CDIM * sizeof(float), stream);
    k_pool<<<2048, 256, 0, stream>>>(h, batch, hg);
    k_readout<<<N_GRAPH, 64, 0, stream>>>(hg, Wr1, br1, Wr2, br2, out);
}

// Round 3
// 1490.262 us; speedup vs baseline: 1.2396x; 1.1261x over previous
//
#include <hip/hip_runtime.h>
#include <math.h>

#define N_NODES 50000
#define N_EDGES 800000
#define N_GRAPH 1024
#define CDIM 128
#define FINDIM 16
#define NL 3

using short8  = __attribute__((ext_vector_type(8))) short;
using floatx4 = __attribute__((ext_vector_type(4))) float;

__device__ __forceinline__ float sspf(float x) {
    // softplus(x) - ln2 via HW v_exp_f32/v_log_f32
    return fmaxf(x, 0.0f) + __logf(1.0f + __expf(-fabsf(x))) - 0.6931471805599453f;
}

__device__ __forceinline__ unsigned short f2bf(float f) {
    unsigned int u = __float_as_uint(f);
    u = u + 0x7FFFu + ((u >> 16) & 1u);   // round-to-nearest-even
    return (unsigned short)(u >> 16);
}

// ---------------------------------------------------------------- embedding (+ fused BN stats)
__global__ void k_fuse(const float* __restrict__ Wl1, const float* __restrict__ bl1,
                       const float* __restrict__ Wl2, const float* __restrict__ bl2,
                       float* __restrict__ Wf, float* __restrict__ bfv) {
    for (int o = threadIdx.x; o < FINDIM * CDIM + CDIM; o += 256) {
        if (o < FINDIM * CDIM) {
            int f = o >> 7, c = o & 127;
            float s = 0.f;
            for (int k = 0; k < CDIM; ++k) s += Wl1[f * CDIM + k] * Wl2[k * CDIM + c];
            Wf[o] = s;
        } else {
            int c = o - FINDIM * CDIM;
            float s = bl2[c];
            for (int k = 0; k < CDIM; ++k) s += bl1[k] * Wl2[k * CDIM + c];
            bfv[c] = s;
        }
    }
}

__global__ void k_embed_bn(const float* __restrict__ x, const float* __restrict__ Wf,
                           const float* __restrict__ bfv, float* __restrict__ h,
                           float* __restrict__ bnsum) {
    __shared__ float wfs[FINDIM * CDIM];
    __shared__ float bfs[CDIM];
    __shared__ float sd[512];
    for (int o = threadIdx.x; o < FINDIM * CDIM; o += 256) wfs[o] = Wf[o];
    if (threadIdx.x < CDIM) bfs[threadIdx.x] = bfv[threadIdx.x];
    __syncthreads();
    int c = threadIdx.x & 127;
    int half = threadIdx.x >> 7;
    float s1 = 0.f, s2 = 0.f;
    for (int base = blockIdx.x * 2; base < N_NODES; base += gridDim.x * 2) {
        int n = base + half;
        if (n < N_NODES) {
            float s = bfs[c];
            const float* xp = x + (size_t)n * FINDIM;
#pragma unroll
            for (int f = 0; f < FINDIM; ++f) s += xp[f] * wfs[f * CDIM + c];
            h[(size_t)n * CDIM + c] = s;
            s1 += s; s2 += s * s;
        }
    }
    sd[threadIdx.x] = s1; sd[256 + threadIdx.x] = s2;
    __syncthreads();
    if (threadIdx.x < 128) {
        atomicAdd(&bnsum[threadIdx.x], sd[threadIdx.x] + sd[threadIdx.x + 128]);
        atomicAdd(&bnsum[128 + threadIdx.x], sd[256 + threadIdx.x] + sd[256 + threadIdx.x + 128]);
    }
}

__global__ void k_bnapply(float* __restrict__ h, const float* __restrict__ bnsum,
                          const float* __restrict__ g, const float* __restrict__ b) {
    const float invN = 1.0f / (float)N_NODES;
    for (size_t i = (size_t)blockIdx.x * 256 + threadIdx.x; i < (size_t)N_NODES * CDIM;
         i += (size_t)gridDim.x * 256) {
        int c = (int)(i & 127);
        float mu  = bnsum[c] * invN;
        float var = bnsum[128 + c] * invN - mu * mu;
        float sc  = g[c] * rsqrtf(var + 1e-5f);
        h[i] = (h[i] - mu) * sc + b[c];
    }
}

// ---------------------------------------------------------------- dst count-sort (once/call)
__global__ void k_hist(const int* __restrict__ edst, int* __restrict__ deg) {
    int e = blockIdx.x * 256 + threadIdx.x;
    if (e < N_EDGES) atomicAdd(&deg[edst[e]], 1);
}

#define SCAN_T 1024
#define CHUNK 49   // 1024*49 = 50176 >= 50000
__global__ void k_scan(const int* __restrict__ deg, int* __restrict__ row_ptr) {
    __shared__ int part[SCAN_T];
    int t = threadIdx.x;
    int begin = t * CHUNK;
    int end   = begin + CHUNK; if (end > N_NODES) end = N_NODES;
    int s = 0;
    for (int i = begin; i < end && i < N_NODES; ++i) s += deg[i];
    part[t] = s;
    __syncthreads();
    for (int off = 1; off < SCAN_T; off <<= 1) {
        int v = (t >= off) ? part[t - off] : 0;
        __syncthreads();
        part[t] += v;
        __syncthreads();
    }
    int run = (t == 0) ? 0 : part[t - 1];
    for (int i = begin; i < end && i < N_NODES; ++i) { row_ptr[i] = run; run += deg[i]; }
    if (t == SCAN_T - 1) row_ptr[N_NODES] = run;
}

__global__ void k_scatter(const int* __restrict__ edst, const int* __restrict__ row_ptr,
                          int* __restrict__ cnt, int* __restrict__ perm) {
    int e = blockIdx.x * 256 + threadIdx.x;
    if (e < N_EDGES) {
        int d = edst[e];
        int pos = row_ptr[d] + atomicAdd(&cnt[d], 1);
        perm[pos] = e;
    }
}

// ---------------------------------------------------------------- node GEMM (bf16 MFMA)
template <int MODE>
__global__ __launch_bounds__(256, 2) void k_ngemm(const float* __restrict__ A,
                                                  const float* __restrict__ B,
                                                  const float* __restrict__ bias,
                                                  float* __restrict__ Out) {
    __shared__ unsigned short WT[128 * 136];
    __shared__ float bs[CDIM];
    for (int o = threadIdx.x; o < CDIM * CDIM; o += 256) {
        int k = o >> 7, c = o & 127;
        WT[c * 136 + k] = f2bf(B[o]);
    }
    if (threadIdx.x < CDIM) bs[threadIdx.x] = bias[threadIdx.x];
    __syncthreads();

    int lane = threadIdx.x & 63, wave = threadIdx.x >> 6;
    int m = lane & 15, q = lane >> 4;
    int rb = blockIdx.x * 64 + wave * 16;
    int row = rb + m;
    if (row > N_NODES - 1) row = N_NODES - 1;

    floatx4 acc[8];
#pragma unroll
    for (int nt = 0; nt < 8; ++nt) acc[nt] = (floatx4){0.f, 0.f, 0.f, 0.f};

#pragma unroll
    for (int kb = 0; kb < 4; ++kb) {
        int k0 = kb * 32 + q * 8;
        const float* ap = A + (size_t)row * CDIM + k0;
        float4 lo = *(const float4*)ap;
        float4 hi = *(const float4*)(ap + 4);
        short8 af;
        af[0] = (short)f2bf(lo.x); af[1] = (short)f2bf(lo.y);
        af[2] = (short)f2bf(lo.z); af[3] = (short)f2bf(lo.w);
        af[4] = (short)f2bf(hi.x); af[5] = (short)f2bf(hi.y);
        af[6] = (short)f2bf(hi.z); af[7] = (short)f2bf(hi.w);
#pragma unroll
        for (int nt = 0; nt < 8; ++nt) {
            short8 bf = *(const short8*)&WT[(nt * 16 + m) * 136 + k0];
            acc[nt] = __builtin_amdgcn_mfma_f32_16x16x32_bf16(af, bf, acc[nt], 0, 0, 0);
        }
    }
#pragma unroll
    for (int nt = 0; nt < 8; ++nt) {
        int c = nt * 16 + m;
#pragma unroll
        for (int r = 0; r < 4; ++r) {
            int orow = rb + q * 4 + r;
            if (orow < N_NODES) {
                float v = acc[nt][r] + bs[c];
                if (MODE == 0) Out[(size_t)orow * CDIM + c] = v;
                else           Out[(size_t)orow * CDIM + c] += sspf(v);
            }
        }
    }
}

// ---------------------------------------------------------------- fused edge kernel (dst-sorted)
// t computed straight into A-frag registers (no TL LDS); hin gather prefetched
// into registers at tile top so the 32 loads overlap t-compute + MFMA.
__global__ __launch_bounds__(256, 2) void k_edge(
    const float* __restrict__ We1, const float* __restrict__ be1,
    const float* __restrict__ We2, const float* __restrict__ be2,
    const float* __restrict__ edge_attr, const float* __restrict__ edge_weight,
    const int* __restrict__ esrc, const int* __restrict__ edst,
    const int* __restrict__ perm,
    const float* __restrict__ hin, float* __restrict__ agg) {
    __shared__ unsigned short WT[128 * 136];
    __shared__ float we1s[3 * CDIM];
    __shared__ float be1s[CDIM];
    __shared__ float be2s[CDIM];
    __shared__ float eas[64 * 3];
    __shared__ float envs[64];
    __shared__ int   srcs[64];
    __shared__ int   dsts[64];

    for (int o = threadIdx.x; o < CDIM * CDIM; o += 256) {
        int k = o >> 7, c = o & 127;
        WT[c * 136 + k] = f2bf(We2[o]);
    }
    for (int o = threadIdx.x; o < 3 * CDIM; o += 256) we1s[o] = We1[o];
    if (threadIdx.x < CDIM) { be1s[threadIdx.x] = be1[threadIdx.x]; be2s[threadIdx.x] = be2[threadIdx.x]; }
    __syncthreads();

    int lane = threadIdx.x & 63, wave = threadIdx.x >> 6;
    int m = lane & 15, q = lane >> 4;

    // all 32 B fragments live in registers for the whole kernel
    short8 breg[4][8];
#pragma unroll
    for (int kb = 0; kb < 4; ++kb)
#pragma unroll
        for (int nt = 0; nt < 8; ++nt)
            breg[kb][nt] = *(const short8*)&WT[(nt * 16 + m) * 136 + kb * 32 + q * 8];

    const int ntiles = N_EDGES / 64;
    int tpb = (ntiles + gridDim.x - 1) / gridDim.x;
    int t0 = blockIdx.x * tpb;
    int t1 = t0 + tpb; if (t1 > ntiles) t1 = ntiles;

    for (int tile = t0; tile < t1; ++tile) {
        int s0 = tile * 64;
        __syncthreads();   // previous iteration's readers done before re-staging
        if (threadIdx.x < 64) {
            int e = perm[s0 + threadIdx.x];
            srcs[threadIdx.x] = esrc[e];
            dsts[threadIdx.x] = edst[e];
            float w = edge_weight[e];
            envs[threadIdx.x] = 0.5f * (__cosf(w * 0.31415926535897932f) + 1.0f);
        } else {
            int idx = threadIdx.x - 64;           // 0..191 -> eas[192]
            int e = perm[s0 + idx / 3];           // redundant perm read, L1-hit
            eas[idx] = edge_attr[(size_t)e * 3 + (idx % 3)];
        }
        __syncthreads();

        // ---- prefetch hin[src] for this thread's 32 epilogue values (stay in flight)
        int el0 = wave * 16 + q * 4;
        int sA[4];
#pragma unroll
        for (int r = 0; r < 4; ++r) sA[r] = srcs[el0 + r];
        float hpre[4][8];
#pragma unroll
        for (int r = 0; r < 4; ++r) {
            const float* hp = hin + (size_t)sA[r] * CDIM + m;
#pragma unroll
            for (int nt = 0; nt < 8; ++nt) hpre[r][nt] = hp[nt * 16];
        }

        // ---- t straight into A-frag regs: A[el = wave*16+m][k = kb*32 + q*8 + j]
        int el = wave * 16 + m;
        float ea0 = eas[el * 3], ea1 = eas[el * 3 + 1], ea2 = eas[el * 3 + 2];
        short8 af[4];
#pragma unroll
        for (int kb = 0; kb < 4; ++kb) {
#pragma unroll
            for (int jj = 0; jj < 4; ++jj) {
                int k = kb * 32 + q * 8 + jj * 2;
                float p0 = fmaf(we1s[k], ea0, fmaf(we1s[CDIM + k], ea1,
                             fmaf(we1s[2 * CDIM + k], ea2, be1s[k])));
                float p1 = fmaf(we1s[k + 1], ea0, fmaf(we1s[CDIM + k + 1], ea1,
                             fmaf(we1s[2 * CDIM + k + 1], ea2, be1s[k + 1])));
                unsigned int pk = (unsigned int)f2bf(sspf(p0)) |
                                  ((unsigned int)f2bf(sspf(p1)) << 16);
                ((unsigned int*)&af[kb])[jj] = pk;
            }
        }

        floatx4 acc[8];
#pragma unroll
        for (int nt = 0; nt < 8; ++nt) acc[nt] = (floatx4){0.f, 0.f, 0.f, 0.f};
#pragma unroll
        for (int kb = 0; kb < 4; ++kb)
#pragma unroll
            for (int nt = 0; nt < 8; ++nt)
                acc[nt] = __builtin_amdgcn_mfma_f32_16x16x32_bf16(af[kb], breg[kb][nt], acc[nt], 0, 0, 0);

        // ---- epilogue: run-merge over the 4 consecutive dst-sorted edges
        int dA[4]; float evA[4];
#pragma unroll
        for (int r = 0; r < 4; ++r) { dA[r] = dsts[el0 + r]; evA[r] = envs[el0 + r]; }
#pragma unroll
        for (int nt = 0; nt < 8; ++nt) {
            int c = nt * 16 + m;
            float bias = be2s[c];
            int cur = dA[0];
            float accv = (acc[nt][0] + bias) * evA[0] * hpre[0][nt];
#pragma unroll
            for (int r = 1; r < 4; ++r) {
                float msg = (acc[nt][r] + bias) * evA[r] * hpre[r][nt];
                if (dA[r] != cur) {
                    atomicAdd(&agg[(size_t)cur * CDIM + c], accv);
                    cur = dA[r]; accv = msg;
                } else {
                    accv += msg;
                }
            }
            atomicAdd(&agg[(size_t)cur * CDIM + c], accv);
        }
    }
}

// ---------------------------------------------------------------- readout
__global__ void k_pool(const float* __restrict__ h, const int* __restrict__ batch,
                       float* __restrict__ hg) {
    for (size_t i = (size_t)blockIdx.x * 256 + threadIdx.x; i < (size_t)N_NODES * CDIM;
         i += (size_t)gridDim.x * 256) {
        int n = (int)(i >> 7), c = (int)(i & 127);
        atomicAdd(&hg[(size_t)batch[n] * CDIM + c], h[i]);
    }
}

__global__ void k_readout(const float* __restrict__ hg, const float* __restrict__ Wr1,
                          const float* __restrict__ br1, const float* __restrict__ Wr2,
                          const float* __restrict__ br2, float* __restrict__ out) {
    __shared__ float hgs[CDIM];
    int g = blockIdx.x;
    for (int o = threadIdx.x; o < CDIM; o += 64) hgs[o] = hg[(size_t)g * CDIM + o];
    __syncthreads();
    int c = threadIdx.x;
    float val = 0.f;
    if (c < 32) {
        float s = br1[c];
        for (int k = 0; k < CDIM; ++k) s += hgs[k] * Wr1[k * 32 + c];
        val = sspf(s) * Wr2[c];
    }
#pragma unroll
    for (int off = 16; off >= 1; off >>= 1) val += __shfl_down(val, off, 32);
    if (c == 0) out[g] = sspf(val + br2[0]);
}

// ---------------------------------------------------------------- launch
extern "C" void kernel_launch(void* const* d_in, const int* in_sizes, int n_in,
                              void* d_out, int out_size, void* d_ws, size_t ws_size,
                              hipStream_t stream) {
    const float* x     = (const float*)d_in[0];
    const int*   eidx  = (const int*)  d_in[1];
    const float* ew    = (const float*)d_in[2];
    const float* ea    = (const float*)d_in[3];
    const int*   batch = (const int*)  d_in[4];
    const float* Wl1   = (const float*)d_in[5];
    const float* bl1   = (const float*)d_in[6];
    const float* Wl2   = (const float*)d_in[7];
    const float* bl2   = (const float*)d_in[8];
    const float* bng   = (const float*)d_in[9];
    const float* bnb   = (const float*)d_in[10];
    const float* Wi_in = (const float*)d_in[11];
    const float* bi_in = (const float*)d_in[12];
    const float* We1   = (const float*)d_in[13];
    const float* be1   = (const float*)d_in[14];
    const float* We2   = (const float*)d_in[15];
    const float* be2   = (const float*)d_in[16];
    const float* Wi_o  = (const float*)d_in[17];
    const float* bi_o  = (const float*)d_in[18];
    const float* Wr1   = (const float*)d_in[19];
    const float* br1   = (const float*)d_in[20];
    const float* Wr2   = (const float*)d_in[21];
    const float* br2   = (const float*)d_in[22];
    float* out = (float*)d_out;

    float* ws    = (float*)d_ws;
    float* h     = ws;                                   // N*128
    float* hin   = h   + (size_t)N_NODES * CDIM;         // N*128
    float* agg   = hin + (size_t)N_NODES * CDIM;         // N*128
    float* hg    = agg + (size_t)N_NODES * CDIM;         // G*128
    float* Wf    = hg  + (size_t)N_GRAPH * CDIM;         // 16*128
    float* bfv   = Wf  + FINDIM * CDIM;                  // 128
    float* bnsum = bfv + CDIM;                           // 256
    int*   deg     = (int*)(bnsum + 256);                // N
    int*   row_ptr = deg + N_NODES;                      // N+1
    int*   cnt     = row_ptr + N_NODES + 1;              // N
    int*   perm    = cnt + N_NODES;                      // E

    const int* esrc = eidx;
    const int* edst = eidx + N_EDGES;

    // ---- edge sort by dst (reused across the 3 layers)
    hipMemsetAsync(deg, 0, (size_t)N_NODES * sizeof(int), stream);
    hipMemsetAsync(cnt, 0, (size_t)N_NODES * sizeof(int), stream);
    k_hist<<<(N_EDGES + 255) / 256, 256, 0, stream>>>(edst, deg);
    k_scan<<<1, SCAN_T, 0, stream>>>(deg, row_ptr);
    k_scatter<<<(N_EDGES + 255) / 256, 256, 0, stream>>>(edst, row_ptr, cnt, perm);

    // ---- embedding + BN (stats fused into embed)
    hipMemsetAsync(bnsum, 0, 256 * sizeof(float), stream);
    k_fuse<<<1, 256, 0, stream>>>(Wl1, bl1, Wl2, bl2, Wf, bfv);
    k_embed_bn<<<512, 256, 0, stream>>>(x, Wf, bfv, h, bnsum);
    k_bnapply<<<1024, 256, 0, stream>>>(h, bnsum, bng, bnb);

    // ---- interaction layers
    const int ngrid = (N_NODES + 63) / 64;
    for (int l = 0; l < NL; ++l) {
        hipMemsetAsync(agg, 0, (size_t)N_NODES * CDIM * sizeof(float), stream);
        k_ngemm<0><<<ngrid, 256, 0, stream>>>(h, Wi_in + (size_t)l * CDIM * CDIM,
                                              bi_in + l * CDIM, hin);
        k_edge<<<512, 256, 0, stream>>>(We1 + l * 3 * CDIM, be1 + l * CDIM,
                                        We2 + (size_t)l * CDIM * CDIM, be2 + l * CDIM,
                                        ea, ew, esrc, edst, perm, hin, agg);
        k_ngemm<1><<<ngrid, 256, 0, stream>>>(agg, Wi_o + (size_t)l * CDIM * CDIM,
                                              bi_o + l * CDIM, h);
    }

    // ---- readout
    hipMemsetAsync(hg, 0, (size_t)N_GRAPH * CDIM * sizeof(float), stream);
    k_pool<<<2048, 256, 0, stream>>>(h, batch, hg);
    k_readout<<<N_GRAPH, 64, 0, stream>>>(hg, Wr1, br1, Wr2, br2, out);
}

// Round 4
// 1418.665 us; speedup vs baseline: 1.3022x; 1.0505x over previous
//
#include <hip/hip_runtime.h>
#include <math.h>

#define N_NODES 50000
#define N_EDGES 800000
#define N_GRAPH 1024
#define CDIM 128
#define FINDIM 16
#define NL 3

using short8  = __attribute__((ext_vector_type(8))) short;
using floatx4 = __attribute__((ext_vector_type(4))) float;

__device__ __forceinline__ float sspf(float x) {
    return fmaxf(x, 0.0f) + __logf(1.0f + __expf(-fabsf(x))) - 0.6931471805599453f;
}

__device__ __forceinline__ unsigned short f2bf(float f) {
    unsigned int u = __float_as_uint(f);
    u = u + 0x7FFFu + ((u >> 16) & 1u);   // round-to-nearest-even
    return (unsigned short)(u >> 16);
}

__device__ __forceinline__ float bf2f(unsigned short h) {
    return __uint_as_float((unsigned int)h << 16);
}

// ---------------------------------------------------------------- embedding (+ fused BN stats)
__global__ void k_fuse(const float* __restrict__ Wl1, const float* __restrict__ bl1,
                       const float* __restrict__ Wl2, const float* __restrict__ bl2,
                       float* __restrict__ Wf, float* __restrict__ bfv) {
    for (int o = threadIdx.x; o < FINDIM * CDIM + CDIM; o += 256) {
        if (o < FINDIM * CDIM) {
            int f = o >> 7, c = o & 127;
            float s = 0.f;
            for (int k = 0; k < CDIM; ++k) s += Wl1[f * CDIM + k] * Wl2[k * CDIM + c];
            Wf[o] = s;
        } else {
            int c = o - FINDIM * CDIM;
            float s = bl2[c];
            for (int k = 0; k < CDIM; ++k) s += bl1[k] * Wl2[k * CDIM + c];
            bfv[c] = s;
        }
    }
}

__global__ void k_embed_bn(const float* __restrict__ x, const float* __restrict__ Wf,
                           const float* __restrict__ bfv, float* __restrict__ h,
                           float* __restrict__ bnsum) {
    __shared__ float wfs[FINDIM * CDIM];
    __shared__ float bfs[CDIM];
    __shared__ float sd[512];
    for (int o = threadIdx.x; o < FINDIM * CDIM; o += 256) wfs[o] = Wf[o];
    if (threadIdx.x < CDIM) bfs[threadIdx.x] = bfv[threadIdx.x];
    __syncthreads();
    int c = threadIdx.x & 127;
    int half = threadIdx.x >> 7;
    float s1 = 0.f, s2 = 0.f;
    for (int base = blockIdx.x * 2; base < N_NODES; base += gridDim.x * 2) {
        int n = base + half;
        if (n < N_NODES) {
            float s = bfs[c];
            const float* xp = x + (size_t)n * FINDIM;
#pragma unroll
            for (int f = 0; f < FINDIM; ++f) s += xp[f] * wfs[f * CDIM + c];
            h[(size_t)n * CDIM + c] = s;
            s1 += s; s2 += s * s;
        }
    }
    sd[threadIdx.x] = s1; sd[256 + threadIdx.x] = s2;
    __syncthreads();
    if (threadIdx.x < 128) {
        atomicAdd(&bnsum[threadIdx.x], sd[threadIdx.x] + sd[threadIdx.x + 128]);
        atomicAdd(&bnsum[128 + threadIdx.x], sd[256 + threadIdx.x] + sd[256 + threadIdx.x + 128]);
    }
}

__global__ void k_bnapply(float* __restrict__ h, const float* __restrict__ bnsum,
                          const float* __restrict__ g, const float* __restrict__ b) {
    const float invN = 1.0f / (float)N_NODES;
    for (size_t i = (size_t)blockIdx.x * 256 + threadIdx.x; i < (size_t)N_NODES * CDIM;
         i += (size_t)gridDim.x * 256) {
        int c = (int)(i & 127);
        float mu  = bnsum[c] * invN;
        float var = bnsum[128 + c] * invN - mu * mu;
        float sc  = g[c] * rsqrtf(var + 1e-5f);
        h[i] = (h[i] - mu) * sc + b[c];
    }
}

// ---------------------------------------------------------------- dst count-sort (once/call)
__global__ void k_hist(const int* __restrict__ edst, int* __restrict__ deg) {
    int e = blockIdx.x * 256 + threadIdx.x;
    if (e < N_EDGES) atomicAdd(&deg[edst[e]], 1);
}

#define SCAN_T 1024
#define CHUNK 49
__global__ void k_scan(const int* __restrict__ deg, int* __restrict__ row_ptr) {
    __shared__ int part[SCAN_T];
    int t = threadIdx.x;
    int begin = t * CHUNK;
    int end   = begin + CHUNK; if (end > N_NODES) end = N_NODES;
    int s = 0;
    for (int i = begin; i < end && i < N_NODES; ++i) s += deg[i];
    part[t] = s;
    __syncthreads();
    for (int off = 1; off < SCAN_T; off <<= 1) {
        int v = (t >= off) ? part[t - off] : 0;
        __syncthreads();
        part[t] += v;
        __syncthreads();
    }
    int run = (t == 0) ? 0 : part[t - 1];
    for (int i = begin; i < end && i < N_NODES; ++i) { row_ptr[i] = run; run += deg[i]; }
    if (t == SCAN_T - 1) row_ptr[N_NODES] = run;
}

__global__ void k_scatter(const int* __restrict__ edst, const int* __restrict__ row_ptr,
                          int* __restrict__ cnt, int* __restrict__ perm) {
    int e = blockIdx.x * 256 + threadIdx.x;
    if (e < N_EDGES) {
        int d = edst[e];
        int pos = row_ptr[d] + atomicAdd(&cnt[d], 1);
        perm[pos] = e;
    }
}

// ---------------------------------------------------------------- node GEMM (bf16 MFMA)
// MODE 0: OutB(bf16) = A@B + bias                         (hin, stored bf16)
// MODE 1: OutF(f32) += ssp(A@B + bias); if ZERO, A = 0    (h update + agg re-zero)
template <int MODE, int ZERO>
__global__ __launch_bounds__(256, 2) void k_ngemm(const float* __restrict__ A,
                                                  const float* __restrict__ B,
                                                  const float* __restrict__ bias,
                                                  float* __restrict__ OutF,
                                                  unsigned short* __restrict__ OutB) {
    __shared__ unsigned short WT[128 * 136];
    __shared__ float bs[CDIM];
    for (int o = threadIdx.x; o < CDIM * CDIM; o += 256) {
        int k = o >> 7, c = o & 127;
        WT[c * 136 + k] = f2bf(B[o]);
    }
    if (threadIdx.x < CDIM) bs[threadIdx.x] = bias[threadIdx.x];
    __syncthreads();

    int lane = threadIdx.x & 63, wave = threadIdx.x >> 6;
    int m = lane & 15, q = lane >> 4;
    int rb = blockIdx.x * 64 + wave * 16;
    int row = rb + m;
    if (row > N_NODES - 1) row = N_NODES - 1;

    floatx4 acc[8];
#pragma unroll
    for (int nt = 0; nt < 8; ++nt) acc[nt] = (floatx4){0.f, 0.f, 0.f, 0.f};

#pragma unroll
    for (int kb = 0; kb < 4; ++kb) {
        int k0 = kb * 32 + q * 8;
        const float* ap = A + (size_t)row * CDIM + k0;
        float4 lo = *(const float4*)ap;
        float4 hi = *(const float4*)(ap + 4);
        short8 af;
        af[0] = (short)f2bf(lo.x); af[1] = (short)f2bf(lo.y);
        af[2] = (short)f2bf(lo.z); af[3] = (short)f2bf(lo.w);
        af[4] = (short)f2bf(hi.x); af[5] = (short)f2bf(hi.y);
        af[6] = (short)f2bf(hi.z); af[7] = (short)f2bf(hi.w);
#pragma unroll
        for (int nt = 0; nt < 8; ++nt) {
            short8 bf = *(const short8*)&WT[(nt * 16 + m) * 136 + k0];
            acc[nt] = __builtin_amdgcn_mfma_f32_16x16x32_bf16(af, bf, acc[nt], 0, 0, 0);
        }
    }
#pragma unroll
    for (int nt = 0; nt < 8; ++nt) {
        int c = nt * 16 + m;
#pragma unroll
        for (int r = 0; r < 4; ++r) {
            int orow = rb + q * 4 + r;
            if (orow < N_NODES) {
                float v = acc[nt][r] + bs[c];
                if (MODE == 0) OutB[(size_t)orow * CDIM + c] = f2bf(v);
                else {
                    OutF[(size_t)orow * CDIM + c] += sspf(v);
                    if (ZERO) ((float*)A)[(size_t)orow * CDIM + c] = 0.f;
                }
            }
        }
    }
}

// ---------------------------------------------------------------- fused edge kernel (dst-sorted)
// B-fragments from LDS (no breg -> 4 blocks/CU), hin gathered as bf16.
__global__ __launch_bounds__(256, 4) void k_edge(
    const float* __restrict__ We1, const float* __restrict__ be1,
    const float* __restrict__ We2, const float* __restrict__ be2,
    const float* __restrict__ edge_attr, const float* __restrict__ edge_weight,
    const int* __restrict__ esrc, const int* __restrict__ edst,
    const int* __restrict__ perm,
    const unsigned short* __restrict__ hin, float* __restrict__ agg) {
    __shared__ unsigned short WT[128 * 136];
    __shared__ float we1s[3 * CDIM];
    __shared__ float be1s[CDIM];
    __shared__ float be2s[CDIM];
    __shared__ float eas[64 * 3];
    __shared__ float envs[64];
    __shared__ int   srcs[64];
    __shared__ int   dsts[64];

    for (int o = threadIdx.x; o < CDIM * CDIM; o += 256) {
        int k = o >> 7, c = o & 127;
        WT[c * 136 + k] = f2bf(We2[o]);
    }
    for (int o = threadIdx.x; o < 3 * CDIM; o += 256) we1s[o] = We1[o];
    if (threadIdx.x < CDIM) { be1s[threadIdx.x] = be1[threadIdx.x]; be2s[threadIdx.x] = be2[threadIdx.x]; }
    __syncthreads();

    int lane = threadIdx.x & 63, wave = threadIdx.x >> 6;
    int m = lane & 15, q = lane >> 4;

    const int ntiles = N_EDGES / 64;
    int tpb = (ntiles + gridDim.x - 1) / gridDim.x;
    int t0 = blockIdx.x * tpb;
    int t1 = t0 + tpb; if (t1 > ntiles) t1 = ntiles;

    for (int tile = t0; tile < t1; ++tile) {
        int s0 = tile * 64;
        __syncthreads();
        if (threadIdx.x < 64) {
            int e = perm[s0 + threadIdx.x];
            srcs[threadIdx.x] = esrc[e];
            dsts[threadIdx.x] = edst[e];
            float w = edge_weight[e];
            envs[threadIdx.x] = 0.5f * (__cosf(w * 0.31415926535897932f) + 1.0f);
        } else {
            int idx = threadIdx.x - 64;           // 0..191 -> eas[192]
            int e = perm[s0 + idx / 3];
            eas[idx] = edge_attr[(size_t)e * 3 + (idx % 3)];
        }
        __syncthreads();

        // ---- prefetch hin[src] (bf16) for this thread's 32 epilogue values
        int el0 = wave * 16 + q * 4;
        unsigned short hpre[4][8];
#pragma unroll
        for (int r = 0; r < 4; ++r) {
            const unsigned short* hp = hin + (size_t)srcs[el0 + r] * CDIM + m;
#pragma unroll
            for (int nt = 0; nt < 8; ++nt) hpre[r][nt] = hp[nt * 16];
        }

        // ---- t straight into A-frag regs: A[el = wave*16+m][k = kb*32 + q*8 + j]
        int el = wave * 16 + m;
        float ea0 = eas[el * 3], ea1 = eas[el * 3 + 1], ea2 = eas[el * 3 + 2];
        short8 af[4];
#pragma unroll
        for (int kb = 0; kb < 4; ++kb) {
#pragma unroll
            for (int jj = 0; jj < 4; ++jj) {
                int k = kb * 32 + q * 8 + jj * 2;
                float p0 = fmaf(we1s[k], ea0, fmaf(we1s[CDIM + k], ea1,
                             fmaf(we1s[2 * CDIM + k], ea2, be1s[k])));
                float p1 = fmaf(we1s[k + 1], ea0, fmaf(we1s[CDIM + k + 1], ea1,
                             fmaf(we1s[2 * CDIM + k + 1], ea2, be1s[k + 1])));
                unsigned int pk = (unsigned int)f2bf(sspf(p0)) |
                                  ((unsigned int)f2bf(sspf(p1)) << 16);
                ((unsigned int*)&af[kb])[jj] = pk;
            }
        }

        floatx4 acc[8];
#pragma unroll
        for (int nt = 0; nt < 8; ++nt) acc[nt] = (floatx4){0.f, 0.f, 0.f, 0.f};
#pragma unroll
        for (int kb = 0; kb < 4; ++kb)
#pragma unroll
            for (int nt = 0; nt < 8; ++nt) {
                short8 bf = *(const short8*)&WT[(nt * 16 + m) * 136 + kb * 32 + q * 8];
                acc[nt] = __builtin_amdgcn_mfma_f32_16x16x32_bf16(af[kb], bf, acc[nt], 0, 0, 0);
            }

        // ---- epilogue: run-merge over the 4 consecutive dst-sorted edges
        int dA[4]; float evA[4];
#pragma unroll
        for (int r = 0; r < 4; ++r) { dA[r] = dsts[el0 + r]; evA[r] = envs[el0 + r]; }
#pragma unroll
        for (int nt = 0; nt < 8; ++nt) {
            int c = nt * 16 + m;
            float bias = be2s[c];
            int cur = dA[0];
            float accv = (acc[nt][0] + bias) * evA[0] * bf2f(hpre[0][nt]);
#pragma unroll
            for (int r = 1; r < 4; ++r) {
                float msg = (acc[nt][r] + bias) * evA[r] * bf2f(hpre[r][nt]);
                if (dA[r] != cur) {
                    atomicAdd(&agg[(size_t)cur * CDIM + c], accv);
                    cur = dA[r]; accv = msg;
                } else {
                    accv += msg;
                }
            }
            atomicAdd(&agg[(size_t)cur * CDIM + c], accv);
        }
    }
}

// ---------------------------------------------------------------- readout
__global__ void k_pool(const float* __restrict__ h, const int* __restrict__ batch,
                       float* __restrict__ hg) {
    for (size_t i = (size_t)blockIdx.x * 256 + threadIdx.x; i < (size_t)N_NODES * CDIM;
         i += (size_t)gridDim.x * 256) {
        int n = (int)(i >> 7), c = (int)(i & 127);
        atomicAdd(&hg[(size_t)batch[n] * CDIM + c], h[i]);
    }
}

__global__ void k_readout(const float* __restrict__ hg, const float* __restrict__ Wr1,
                          const float* __restrict__ br1, const float* __restrict__ Wr2,
                          const float* __restrict__ br2, float* __restrict__ out) {
    __shared__ float hgs[CDIM];
    int g = blockIdx.x;
    for (int o = threadIdx.x; o < CDIM; o += 64) hgs[o] = hg[(size_t)g * CDIM + o];
    __syncthreads();
    int c = threadIdx.x;
    float val = 0.f;
    if (c < 32) {
        float s = br1[c];
        for (int k = 0; k < CDIM; ++k) s += hgs[k] * Wr1[k * 32 + c];
        val = sspf(s) * Wr2[c];
    }
#pragma unroll
    for (int off = 16; off >= 1; off >>= 1) val += __shfl_down(val, off, 32);
    if (c == 0) out[g] = sspf(val + br2[0]);
}

// ---------------------------------------------------------------- launch
extern "C" void kernel_launch(void* const* d_in, const int* in_sizes, int n_in,
                              void* d_out, int out_size, void* d_ws, size_t ws_size,
                              hipStream_t stream) {
    const float* x     = (const float*)d_in[0];
    const int*   eidx  = (const int*)  d_in[1];
    const float* ew    = (const float*)d_in[2];
    const float* ea    = (const float*)d_in[3];
    const int*   batch = (const int*)  d_in[4];
    const float* Wl1   = (const float*)d_in[5];
    const float* bl1   = (const float*)d_in[6];
    const float* Wl2   = (const float*)d_in[7];
    const float* bl2   = (const float*)d_in[8];
    const float* bng   = (const float*)d_in[9];
    const float* bnb   = (const float*)d_in[10];
    const float* Wi_in = (const float*)d_in[11];
    const float* bi_in = (const float*)d_in[12];
    const float* We1   = (const float*)d_in[13];
    const float* be1   = (const float*)d_in[14];
    const float* We2   = (const float*)d_in[15];
    const float* be2   = (const float*)d_in[16];
    const float* Wi_o  = (const float*)d_in[17];
    const float* bi_o  = (const float*)d_in[18];
    const float* Wr1   = (const float*)d_in[19];
    const float* br1   = (const float*)d_in[20];
    const float* Wr2   = (const float*)d_in[21];
    const float* br2   = (const float*)d_in[22];
    float* out = (float*)d_out;

    float* ws    = (float*)d_ws;
    float* h     = ws;                                   // N*128 f32
    unsigned short* hinb = (unsigned short*)(h + (size_t)N_NODES * CDIM);  // N*128 bf16 (occupies N*64 floats)
    float* agg   = (float*)(hinb + (size_t)N_NODES * CDIM);                // N*128 f32
    float* hg    = agg + (size_t)N_NODES * CDIM;         // G*128
    float* Wf    = hg  + (size_t)N_GRAPH * CDIM;         // 16*128
    float* bfv   = Wf  + FINDIM * CDIM;                  // 128
    float* bnsum = bfv + CDIM;                           // 256
    int*   deg     = (int*)(bnsum + 256);                // N
    int*   row_ptr = deg + N_NODES;                      // N+1
    int*   cnt     = row_ptr + N_NODES + 1;              // N
    int*   perm    = cnt + N_NODES;                      // E

    const int* esrc = eidx;
    const int* edst = eidx + N_EDGES;

    // ---- edge sort by dst (reused across the 3 layers)
    hipMemsetAsync(deg, 0, (size_t)N_NODES * sizeof(int), stream);
    hipMemsetAsync(cnt, 0, (size_t)N_NODES * sizeof(int), stream);
    k_hist<<<(N_EDGES + 255) / 256, 256, 0, stream>>>(edst, deg);
    k_scan<<<1, SCAN_T, 0, stream>>>(deg, row_ptr);
    k_scatter<<<(N_EDGES + 255) / 256, 256, 0, stream>>>(edst, row_ptr, cnt, perm);

    // ---- embedding + BN
    hipMemsetAsync(bnsum, 0, 256 * sizeof(float), stream);
    k_fuse<<<1, 256, 0, stream>>>(Wl1, bl1, Wl2, bl2, Wf, bfv);
    k_embed_bn<<<512, 256, 0, stream>>>(x, Wf, bfv, h, bnsum);
    k_bnapply<<<1024, 256, 0, stream>>>(h, bnsum, bng, bnb);

    // ---- interaction layers (agg zeroed once; k_ngemm<1,1> re-zeroes for next layer)
    hipMemsetAsync(agg, 0, (size_t)N_NODES * CDIM * sizeof(float), stream);
    const int ngrid = (N_NODES + 63) / 64;
    for (int l = 0; l < NL; ++l) {
        k_ngemm<0, 0><<<ngrid, 256, 0, stream>>>(h, Wi_in + (size_t)l * CDIM * CDIM,
                                                 bi_in + l * CDIM, nullptr, hinb);
        k_edge<<<1024, 256, 0, stream>>>(We1 + l * 3 * CDIM, be1 + l * CDIM,
                                         We2 + (size_t)l * CDIM * CDIM, be2 + l * CDIM,
                                         ea, ew, esrc, edst, perm, hinb, agg);
        if (l < NL - 1)
            k_ngemm<1, 1><<<ngrid, 256, 0, stream>>>(agg, Wi_o + (size_t)l * CDIM * CDIM,
                                                     bi_o + l * CDIM, h, nullptr);
        else
            k_ngemm<1, 0><<<ngrid, 256, 0, stream>>>(agg, Wi_o + (size_t)l * CDIM * CDIM,
                                                     bi_o + l * CDIM, h, nullptr);
    }

    // ---- readout
    hipMemsetAsync(hg, 0, (size_t)N_GRAPH * CDIM * sizeof(float), stream);
    k_pool<<<2048, 256, 0, stream>>>(h, batch, hg);
    k_readout<<<N_GRAPH, 64, 0, stream>>>(hg, Wr1, br1, Wr2, br2, out);
}